// Round 7
// baseline (443.935 us; speedup 1.0000x reference)
//
#include <hip/hip_runtime.h>
#include <hip/hip_bf16.h>

// MLA prefill: B=1, S=2048, H=4096, NH=16, QK_NOPE=128, QK_ROPE=64, V=128
// f32 device tensors; bf16 MFMA internally. Attention: split-K flash (768
// blocks, every block <=16 K-steps) + f32 partial merge. GEMMs: m97 128x128
// tile + bijective XCD-chunked swizzle (T1/m204) + LDS DOUBLE-BUFFER with
// cross-barrier global_load_lds prefetch: per step {barrier (drains last
// prefetch via compiler's vmcnt(0)) -> issue gll for tile k+1 into buf^1 ->
// compute tile k from buf^0}. Staging latency overlaps compute; 1 barrier
// per step (was 2). LDS 64KB/block; all GEMM grids are <=2.1 blocks/CU so
// the 2-block LDS cap costs nothing.

typedef short bf16x8 __attribute__((ext_vector_type(8)));
typedef float f32x4  __attribute__((ext_vector_type(4)));

#if __has_builtin(__builtin_amdgcn_global_load_lds)
#define USE_GLL 1
#else
#define USE_GLL 0
#endif

__device__ __forceinline__ void stage16(const void* g, void* l) {
#if USE_GLL
    __builtin_amdgcn_global_load_lds(
        (__attribute__((address_space(1))) void*)(g),
        (__attribute__((address_space(3))) void*)(l), 16, 0, 0);
#else
    *(uint4*)l = *(const uint4*)g;
#endif
}

#define LOG2E 1.4426950408889634f

__device__ __forceinline__ short bf16_bits(float v) {
    union { __hip_bfloat16 h; short s; } u;
    u.h = __float2bfloat16(v);
    return u.s;
}

// Partial-O storage split across free workspace gaps (f32, 32KB/pid).
__device__ __forceinline__ const float* po_base(const float* b0, const float* b1,
                                                const float* b2, int pid) {
    if (pid < 288) return b0 + (size_t)pid * 8192;
    if (pid < 448) return b1 + (size_t)(pid - 288) * 8192;
    return b2 + (size_t)(pid - 448) * 8192;
}

// ---------------------------------------------------------------------------
// Elementwise helpers
// ---------------------------------------------------------------------------
__global__ __launch_bounds__(256)
void cvt_bf16(const float* __restrict__ s, __hip_bfloat16* __restrict__ d, int nq) {
    int i = blockIdx.x * 256 + threadIdx.x;
    if (i >= nq) return;
    float4 v = ((const float4*)s)[i];
    union { uint2 u; __hip_bfloat16 h[4]; } r;
    r.h[0] = __float2bfloat16(v.x); r.h[1] = __float2bfloat16(v.y);
    r.h[2] = __float2bfloat16(v.z); r.h[3] = __float2bfloat16(v.w);
    ((uint2*)d)[i] = r.u;
}

__device__ __forceinline__ void cvt4(const float* __restrict__ s,
                                     __hip_bfloat16* __restrict__ d, int i) {
    float4 v = ((const float4*)s)[i];
    union { uint2 u; __hip_bfloat16 h[4]; } r;
    r.h[0] = __float2bfloat16(v.x); r.h[1] = __float2bfloat16(v.y);
    r.h[2] = __float2bfloat16(v.z); r.h[3] = __float2bfloat16(v.w);
    ((uint2*)d)[i] = r.u;
}

// wq_a (1572864 quads) + wkv_a (589824) + zero pad rows (65536) -> W0
__global__ __launch_bounds__(256)
void cvt_prep_a(const float* __restrict__ wq_a, const float* __restrict__ wkv_a,
                __hip_bfloat16* __restrict__ W0) {
    int i = blockIdx.x * 256 + threadIdx.x;   // 2228224 total
    if (i >= 2228224) return;
    if (i < 1572864)       cvt4(wq_a, W0, i);
    else if (i < 2162688) {
        float4 v = ((const float4*)wkv_a)[i - 1572864];
        union { uint2 u; __hip_bfloat16 h[4]; } r;
        r.h[0] = __float2bfloat16(v.x); r.h[1] = __float2bfloat16(v.y);
        r.h[2] = __float2bfloat16(v.z); r.h[3] = __float2bfloat16(v.w);
        ((uint2*)W0)[i] = r.u;
    } else                 ((uint2*)W0)[i] = make_uint2(0u, 0u);
}

// wq_b (1179648 quads) + wkv_b (524288 quads)
__global__ __launch_bounds__(256)
void cvt_prep_b(const float* __restrict__ wq_b, const float* __restrict__ wkv_b,
                __hip_bfloat16* __restrict__ wq_bB, __hip_bfloat16* __restrict__ wkv_bB) {
    int i = blockIdx.x * 256 + threadIdx.x;   // 1703936 total
    if (i >= 1703936) return;
    if (i < 1179648) cvt4(wq_b, wq_bB, i);
    else {
        int j = i - 1179648;
        float4 v = ((const float4*)wkv_b)[j];
        union { uint2 u; __hip_bfloat16 h[4]; } r;
        r.h[0] = __float2bfloat16(v.x); r.h[1] = __float2bfloat16(v.y);
        r.h[2] = __float2bfloat16(v.z); r.h[3] = __float2bfloat16(v.w);
        ((uint2*)wkv_bB)[j] = r.u;
    }
}

__global__ __launch_bounds__(256)
void zero_f32(float* __restrict__ p, int n4) {
    int i = blockIdx.x * 256 + threadIdx.x;
    if (i < n4) ((float4*)p)[i] = float4{0.f, 0.f, 0.f, 0.f};
}

// ---------------------------------------------------------------------------
// m97-style GEMM: C = A[M,K] * B[*,K]^T, bf16 in, fp32 acc, 128x128 tile,
// LDS double-buffer + cross-barrier gll prefetch.
// OUTMODE: 0 = bf16 store, 1 = f32 store, 2 = f32 atomicAdd (split-K).
// Bijective XCD-chunked swizzle (m204).
// ---------------------------------------------------------------------------
template<int OUTMODE>
__global__ __launch_bounds__(256)
void gemm_lds(const __hip_bfloat16* __restrict__ A,
              const __hip_bfloat16* __restrict__ B,
              void* __restrict__ C,
              int K, int Cld, int Nlim, int ksteps) {
    __shared__ __align__(16) short As[2][128 * 64];
    __shared__ __align__(16) short Bs[2][128 * 64];

    const int tid  = threadIdx.x;
    const int lane = tid & 63;
    const int wave = tid >> 6;
    const int quad = lane >> 4;
    const int l16  = lane & 15;

    // XCD-chunked bijective remap of the flat block id
    const int gx = gridDim.x, gy = gridDim.y;
    const int nwg = gx * gy * gridDim.z;
    const int f   = blockIdx.x + gx * (blockIdx.y + gy * blockIdx.z);
    const int qc  = nwg >> 3, rc = nwg & 7;
    const int xcd = f & 7, idx = f >> 3;
    const int neu = (xcd < rc ? xcd * (qc + 1) : rc * (qc + 1) + (xcd - rc) * qc) + idx;
    const int bx  = neu % gx;
    const int t1  = neu / gx;
    const int by  = t1 % gy;
    const int bz  = t1 / gy;

    const int m0 = by * 128;
    const int n0 = bx * 128;
    const int wm = (wave >> 1) * 64;
    const int wn = (wave & 1) * 64;
    const int kbeg = bz * ksteps * 64;

    const int lrow = lane >> 3;
    const int lchk = lane & 7;
    const int sb   = (lchk ^ lrow) * 16;

    f32x4 acc[4][4];
    #pragma unroll
    for (int i = 0; i < 4; i++)
        #pragma unroll
        for (int j = 0; j < 4; j++)
            acc[i][j] = f32x4{0.f, 0.f, 0.f, 0.f};

    const size_t str = (size_t)K * 2;
    const char* Ab = (const char*)A;
    const char* Bb = (const char*)B;

    auto stage_tile = [&](int buf, int kt) {
        const size_t koff = (size_t)(kbeg + kt * 64) * 2;
        #pragma unroll
        for (int t = 0; t < 4; t++) {
            const int row = wave * 32 + t * 8 + lrow;
            stage16(Ab + (size_t)(m0 + row) * str + koff + sb,
                    (char*)As[buf] + row * 128 + lchk * 16);
            stage16(Bb + (size_t)(n0 + row) * str + koff + sb,
                    (char*)Bs[buf] + row * 128 + lchk * 16);
        }
    };

    stage_tile(0, 0);                       // prologue prefetch

    for (int kk = 0; kk < ksteps; kk++) {
        // Drains the outstanding gll prefetch (compiler emits vmcnt(0)
        // before s_barrier) AND releases the buffer computed last step.
        __syncthreads();
        if (kk + 1 < ksteps) stage_tile((kk + 1) & 1, kk + 1);

        const short* Asb = As[kk & 1];
        const short* Bsb = Bs[kk & 1];
        #pragma unroll
        for (int ks = 0; ks < 2; ks++) {
            const int ca = ((ks * 4 + quad) ^ (l16 & 7)) * 8;
            bf16x8 af[4], bfr[4];
            #pragma unroll
            for (int mi = 0; mi < 4; mi++)
                af[mi] = *(const bf16x8*)(&Asb[(wm + mi * 16 + l16) * 64 + ca]);
            #pragma unroll
            for (int ni = 0; ni < 4; ni++)
                bfr[ni] = *(const bf16x8*)(&Bsb[(wn + ni * 16 + l16) * 64 + ca]);
            #pragma unroll
            for (int mi = 0; mi < 4; mi++)
                #pragma unroll
                for (int ni = 0; ni < 4; ni++)
                    acc[mi][ni] = __builtin_amdgcn_mfma_f32_16x16x32_bf16(
                        af[mi], bfr[ni], acc[mi][ni], 0, 0, 0);
        }
    }

    #pragma unroll
    for (int mi = 0; mi < 4; mi++)
        #pragma unroll
        for (int ni = 0; ni < 4; ni++) {
            const int col = n0 + wn + ni * 16 + l16;
            if (col >= Nlim) continue;
            #pragma unroll
            for (int r = 0; r < 4; r++) {
                const int row = m0 + wm + mi * 16 + quad * 4 + r;
                const float v = acc[mi][ni][r];
                if (OUTMODE == 0)
                    ((__hip_bfloat16*)C)[(size_t)row * Cld + col] = __float2bfloat16(v);
                else if (OUTMODE == 1)
                    ((float*)C)[(size_t)row * Cld + col] = v;
                else
                    atomicAdd(&((float*)C)[(size_t)row * Cld + col], v);
            }
        }
}

// ---------------------------------------------------------------------------
// Fused post-GEMM: blocks [0,2048)=rms(q_lat), [2048,4096)=rms(ckv),
// [4096,4608)=kpe copy.
// ---------------------------------------------------------------------------
__global__ __launch_bounds__(256)
void post_fused(const float* __restrict__ fused,
                const float* __restrict__ qw, const float* __restrict__ kvw,
                __hip_bfloat16* __restrict__ q_lat, __hip_bfloat16* __restrict__ ckv,
                float* __restrict__ kpe) {
    const int b = blockIdx.x;
    if (b >= 4096) {
        int i = (b - 4096) * 256 + threadIdx.x;   // 131072 total
        int r = i >> 6, c = i & 63;
        kpe[i] = fused[(size_t)r * 2112 + 2048 + c];
        return;
    }
    const bool isq = (b < 2048);
    const int row = isq ? b : b - 2048;
    const int W  = isq ? 1536 : 512;
    const float* x = fused + (size_t)row * 2112 + (isq ? 0 : 1536);
    const float* w = isq ? qw : kvw;
    __hip_bfloat16* Y = (isq ? q_lat + (size_t)row * 1536 : ckv + (size_t)row * 512);
    float ss = 0.f;
    for (int i = threadIdx.x; i < W; i += 256) { float v = x[i]; ss += v * v; }
    for (int off = 32; off; off >>= 1) ss += __shfl_down(ss, off);
    __shared__ float red[4];
    int lane = threadIdx.x & 63, wv = threadIdx.x >> 6;
    if (lane == 0) red[wv] = ss;
    __syncthreads();
    float tot = red[0] + red[1] + red[2] + red[3];
    float inv = rsqrtf(tot / (float)W + 1e-6f);
    for (int i = threadIdx.x; i < W; i += 256)
        Y[i] = __float2bfloat16(x[i] * inv * w[i]);
}

// ---------------------------------------------------------------------------
// RoPE (q in-place) + build kfT[h][c][s]: 16B cell c holds k=c*8..c*8+7.
// ---------------------------------------------------------------------------
__global__ __launch_bounds__(256)
void rope_assemble(__hip_bfloat16* __restrict__ q,           // [S,16,192] in-place
                   const __hip_bfloat16* __restrict__ kvexp, // [S,16,256]
                   const float* __restrict__ kpe_in,         // [S,64]
                   __hip_bfloat16* __restrict__ kfT) {       // [16][24][2048] cells
    int s = blockIdx.x;
    int tid = threadIdx.x;
    __shared__ float cs[32], sn[32];
    __shared__ __hip_bfloat16 kpe[64];
    if (tid < 32) {
        float inv = expf(-(float)tid * (logf(10000.0f) / 32.0f));
        float ang = (float)s * inv;
        cs[tid] = cosf(ang);
        sn[tid] = sinf(ang);
    }
    __syncthreads();
    if (tid < 32) {
        float x1 = kpe_in[(size_t)s * 64 + tid];
        float x2 = kpe_in[(size_t)s * 64 + 32 + tid];
        kpe[tid]      = __float2bfloat16(x1 * cs[tid] - x2 * sn[tid]);
        kpe[tid + 32] = __float2bfloat16(x2 * cs[tid] + x1 * sn[tid]);
    }
    for (int p = tid; p < 512; p += 256) {
        int h = p >> 5, j = p & 31;
        size_t base = (size_t)s * 3072 + h * 192 + 128;
        float x1 = __bfloat162float(q[base + j]);
        float x2 = __bfloat162float(q[base + j + 32]);
        q[base + j]      = __float2bfloat16(x1 * cs[j] - x2 * sn[j]);
        q[base + j + 32] = __float2bfloat16(x2 * cs[j] + x1 * sn[j]);
    }
    __syncthreads();
    for (int i = tid; i < 16 * 192; i += 256) {
        int h = i / 192, d = i % 192;
        __hip_bfloat16 v = (d < 128) ? kvexp[(size_t)s * 4096 + h * 256 + d]
                                     : kpe[d - 128];
        kfT[((size_t)(h * 24 + (d >> 3)) * 2048 + s) * 8 + (d & 7)] = v;
    }
}

// ---------------------------------------------------------------------------
// vT2[h][sc][d]: 16B cell holds V[s=sc*8..sc*8+7][d] transposed per 8-s group.
// ---------------------------------------------------------------------------
__global__ __launch_bounds__(256)
void transpose_v(const __hip_bfloat16* __restrict__ kvexp,
                 __hip_bfloat16* __restrict__ vT2) {
    __shared__ short t[64 * 72];
    int s0 = blockIdx.x * 64, d0 = blockIdx.y * 64, h = blockIdx.z;
    int c = threadIdx.x & 63;
    int r4 = threadIdx.x >> 6;
    for (int i = 0; i < 16; i++) {
        int r = r4 * 16 + i;
        t[r * 72 + c] = *(const short*)&kvexp[(size_t)(s0 + r) * 4096 + h * 256 + 128 + d0 + c];
    }
    __syncthreads();
    for (int it = 0; it < 2; it++) {
        int scl = it * 4 + (threadIdx.x >> 6);  // 0..7 local s-chunk
        int d   = threadIdx.x & 63;
        union { uint4 u; short sh[8]; } pk;
        #pragma unroll
        for (int e = 0; e < 8; e++) pk.sh[e] = t[(scl * 8 + e) * 72 + d];
        size_t cell = ((size_t)h * 256 + blockIdx.x * 8 + scl) * 128 + d0 + d;
        ((uint4*)vT2)[cell] = pk.u;
    }
}

// ---------------------------------------------------------------------------
// Flash attention, split-K: 768 blocks (see round-4 comment).
// ---------------------------------------------------------------------------
__global__ __launch_bounds__(256, 3)
void attn_kernel(const __hip_bfloat16* __restrict__ qb,   // [S,16,192]
                 const __hip_bfloat16* __restrict__ kfT,  // [16][24][2048] cells
                 const __hip_bfloat16* __restrict__ vT2,  // [16][256][128] cells
                 __hip_bfloat16* __restrict__ out,        // [S,16,128]
                 float* __restrict__ po0, float* __restrict__ po1,
                 float* __restrict__ po2,
                 float* __restrict__ pm, float* __restrict__ pl) {
    const int b = blockIdx.x;
    int h, qt, ktbeg, ktend, pid;
    if (b < 256) {
        h = b >> 4; qt = b & 15;
        ktbeg = 0; ktend = qt + 1; pid = -1;
    } else {
        const int idx  = (b - 256) & 255;
        const int part = (b - 256) >> 8;
        h = idx >> 4; qt = 31 - (idx & 15);
        const int n0 = (qt + 2) >> 1;          // ceil((qt+1)/2)
        ktbeg = part ? n0 : 0;
        ktend = part ? qt + 1 : n0;
        pid = part * 256 + idx;
    }
    const int q0   = qt * 64;
    const int tid  = threadIdx.x;
    const int wave = tid >> 6;
    const int lane = tid & 63;
    const int quad = lane >> 4;
    const int l16  = lane & 15;

    __shared__ __align__(16) short Ks2[24 * 64 * 8];   // 24 KB
    __shared__ __align__(16) short Vs2[ 8 * 128 * 8];  // 16 KB
    __shared__ __align__(16) short Ps2[ 8 * 64 * 8];   //  8 KB

    const float scale = 0.07216878364870322f;  // 192^-0.5

    // Q fragments, pre-scaled: A[m=l16][k=quad*8+j]
    bf16x8 qfr[6];
    {
        int row = q0 + wave * 16 + l16;
        const __hip_bfloat16* qrow = qb + ((size_t)row * 16 + h) * 192;
        for (int ks = 0; ks < 6; ks++) {
            union { bf16x8 v; __hip_bfloat16 h8[8]; } u;
            u.v = *(const bf16x8*)(qrow + ks * 32 + quad * 8);
            #pragma unroll
            for (int e = 0; e < 8; e++)
                u.h8[e] = __float2bfloat16(__bfloat162float(u.h8[e]) * scale);
            qfr[ks] = u.v;
        }
    }

    f32x4 o_acc[8];
    #pragma unroll
    for (int i = 0; i < 8; i++) o_acc[i] = f32x4{0.f, 0.f, 0.f, 0.f};
    float m_i[4], l_i[4];
    #pragma unroll
    for (int r = 0; r < 4; r++) { m_i[r] = -__builtin_inff(); l_i[r] = 0.f; }

    const char* kfb = (const char*)kfT;
    const char* vtb = (const char*)vT2;

    for (int kt = ktbeg; kt < ktend; kt++) {
        if (kt != ktbeg) __syncthreads();
        #pragma unroll
        for (int j = 0; j < 6; j++) {
            int c = wave * 6 + j;
            stage16(kfb + (((size_t)(h * 24 + c) * 2048) + kt * 64 + lane) * 16,
                    (char*)Ks2 + (c * 64 + lane) * 16);
        }
        #pragma unroll
        for (int j = 0; j < 4; j++) {
            int c  = wave * 2 + (j >> 1);
            int hd = j & 1;
            stage16(vtb + (((size_t)(h * 256 + kt * 8 + c) * 128) + hd * 64 + lane) * 16,
                    (char*)Vs2 + (c * 128 + hd * 64 + lane) * 16);
        }
        __syncthreads();

        f32x4 sc[4];
        #pragma unroll
        for (int n = 0; n < 4; n++) sc[n] = f32x4{0.f, 0.f, 0.f, 0.f};
        #pragma unroll
        for (int ks = 0; ks < 6; ks++)
            #pragma unroll
            for (int n = 0; n < 4; n++) {
                bf16x8 kb = *(const bf16x8*)(&Ks2[((ks * 4 + quad) * 64 + n * 16 + l16) * 8]);
                sc[n] = __builtin_amdgcn_mfma_f32_16x16x32_bf16(qfr[ks], kb, sc[n], 0, 0, 0);
            }

        const bool last = (kt == qt);
        float tmax[4], rsum[4], alpha[4];
        #pragma unroll
        for (int r = 0; r < 4; r++) tmax[r] = -__builtin_inff();
        #pragma unroll
        for (int n = 0; n < 4; n++)
            #pragma unroll
            for (int r = 0; r < 4; r++) {
                float v = sc[n][r];
                if (last && (kt * 64 + n * 16 + l16) > (q0 + wave * 16 + quad * 4 + r))
                    v = -__builtin_inff();
                sc[n][r] = v;
                tmax[r] = fmaxf(tmax[r], v);
            }
        #pragma unroll
        for (int r = 0; r < 4; r++)
            #pragma unroll
            for (int off = 1; off < 16; off <<= 1)
                tmax[r] = fmaxf(tmax[r], __shfl_xor(tmax[r], off));
        #pragma unroll
        for (int r = 0; r < 4; r++) {
            float mn = fmaxf(m_i[r], tmax[r]);
            alpha[r] = exp2f((m_i[r] - mn) * LOG2E);
            m_i[r] = mn;
            rsum[r] = 0.f;
        }
        #pragma unroll
        for (int n = 0; n < 4; n++)
            #pragma unroll
            for (int r = 0; r < 4; r++) {
                float p2 = exp2f((sc[n][r] - m_i[r]) * LOG2E);
                sc[n][r] = p2;
                rsum[r] += p2;
            }
        #pragma unroll
        for (int r = 0; r < 4; r++) {
            #pragma unroll
            for (int off = 1; off < 16; off <<= 1)
                rsum[r] += __shfl_xor(rsum[r], off);
            l_i[r] = l_i[r] * alpha[r] + rsum[r];
        }
        #pragma unroll
        for (int n = 0; n < 4; n++)
            #pragma unroll
            for (int r = 0; r < 4; r++)
                Ps2[((n * 2 + (l16 >> 3)) * 64 + wave * 16 + quad * 4 + r) * 8 + (l16 & 7)] =
                    bf16_bits(sc[n][r]);
        #pragma unroll
        for (int d = 0; d < 8; d++)
            #pragma unroll
            for (int r = 0; r < 4; r++)
                o_acc[d][r] *= alpha[r];
        #pragma unroll
        for (int ks2 = 0; ks2 < 2; ks2++) {
            bf16x8 pa = *(const bf16x8*)(&Ps2[((ks2 * 4 + quad) * 64 + wave * 16 + l16) * 8]);
            #pragma unroll
            for (int dg = 0; dg < 8; dg++) {
                bf16x8 vb = *(const bf16x8*)(&Vs2[((ks2 * 4 + quad) * 128 + dg * 16 + l16) * 8]);
                o_acc[dg] = __builtin_amdgcn_mfma_f32_16x16x32_bf16(pa, vb, o_acc[dg], 0, 0, 0);
            }
        }
    }

    if (pid < 0) {
        #pragma unroll
        for (int dg = 0; dg < 8; dg++)
            #pragma unroll
            for (int r = 0; r < 4; r++) {
                int row = q0 + wave * 16 + quad * 4 + r;
                float v = o_acc[dg][r] / l_i[r];
                out[((size_t)row * 16 + h) * 128 + dg * 16 + l16] = __float2bfloat16(v);
            }
    } else {
        float* pob = const_cast<float*>(po_base(po0, po1, po2, pid));
        #pragma unroll
        for (int dg = 0; dg < 8; dg++)
            #pragma unroll
            for (int r = 0; r < 4; r++) {
                int lr = wave * 16 + quad * 4 + r;
                pob[(size_t)lr * 128 + dg * 16 + l16] = o_acc[dg][r];
            }
        if (l16 == 0) {
            #pragma unroll
            for (int r = 0; r < 4; r++) {
                int lr = wave * 16 + quad * 4 + r;
                pm[pid * 64 + lr] = m_i[r];
                pl[pid * 64 + lr] = l_i[r];
            }
        }
    }
}

// ---------------------------------------------------------------------------
__global__ __launch_bounds__(256)
void attn_merge(const float* __restrict__ po0, const float* __restrict__ po1,
                const float* __restrict__ po2,
                const float* __restrict__ pm, const float* __restrict__ pl,
                __hip_bfloat16* __restrict__ out) {
    const int idx = blockIdx.x;            // 0..255
    const int h  = idx >> 4;
    const int qt = 31 - (idx & 15);
    const int q0 = qt * 64;
    const int t   = threadIdx.x;
    const int row = t >> 2;
    const int c0  = (t & 3) << 5;
    const int pid0 = idx, pid1 = 256 + idx;
    const float m0 = pm[pid0 * 64 + row], m1 = pm[pid1 * 64 + row];
    const float l0 = pl[pid0 * 64 + row], l1 = pl[pid1 * 64 + row];
    const float M  = fmaxf(m0, m1);
    const float e0 = exp2f((m0 - M) * LOG2E);
    const float e1 = exp2f((m1 - M) * LOG2E);
    const float inv = 1.f / (e0 * l0 + e1 * l1);
    const float* p0 = po_base(po0, po1, po2, pid0) + (size_t)row * 128 + c0;
    const float* p1 = po_base(po0, po1, po2, pid1) + (size_t)row * 128 + c0;
    __hip_bfloat16* o = out + ((size_t)(q0 + row) * 16 + h) * 128 + c0;
    #pragma unroll
    for (int c = 0; c < 32; c += 4) {
        float4 a = *(const float4*)(p0 + c);
        float4 bb = *(const float4*)(p1 + c);
        union { uint2 u; __hip_bfloat16 hh[4]; } w;
        w.hh[0] = __float2bfloat16((e0 * a.x + e1 * bb.x) * inv);
        w.hh[1] = __float2bfloat16((e0 * a.y + e1 * bb.y) * inv);
        w.hh[2] = __float2bfloat16((e0 * a.z + e1 * bb.z) * inv);
        w.hh[3] = __float2bfloat16((e0 * a.w + e1 * bb.w) * inv);
        *(uint2*)(o + c) = w.u;
    }
}

// ---------------------------------------------------------------------------
extern "C" void kernel_launch(void* const* d_in, const int* in_sizes, int n_in,
                              void* d_out, int out_size, void* d_ws, size_t ws_size,
                              hipStream_t stream) {
    const float* hidden = (const float*)d_in[0];
    const float* wq_a   = (const float*)d_in[2];
    const float* q_a_w  = (const float*)d_in[3];
    const float* wq_b   = (const float*)d_in[4];
    const float* wkv_a  = (const float*)d_in[5];
    const float* kv_a_w = (const float*)d_in[6];
    const float* wkv_b  = (const float*)d_in[7];
    const float* wo     = (const float*)d_in[8];
    float* out = (float*)d_out;

    char* ws = (char*)d_ws;
    __hip_bfloat16* hiddenB = (__hip_bfloat16*)(ws + 0);          // [2048,4096]   s0-s1
    __hip_bfloat16* wq_bB   = (__hip_bfloat16*)(ws + 0);          // [3072,1536]   s3-s4
    __hip_bfloat16* kfT     = (__hip_bfloat16*)(ws + 0);          // [16][24][2048]c s6-s8
    __hip_bfloat16* W0      = (__hip_bfloat16*)(ws + 16777216);   // [2176,4096]   s0-s1
    __hip_bfloat16* kv_exp  = (__hip_bfloat16*)(ws + 16777216);   // [2048,16,256] s5-s7
    __hip_bfloat16* attn_o  = (__hip_bfloat16*)(ws + 16777216);   // [2048,2048]   s8-s9
    float*          fused   = (float*)(ws + 34603008);            // [2048,2112]   s1-s2
    __hip_bfloat16* qb      = (__hip_bfloat16*)(ws + 34603008);   // [2048,16,192] s4-s8
    __hip_bfloat16* woB     = (__hip_bfloat16*)(ws + 34603008);   // [4096,2048]   s9
    __hip_bfloat16* wkv_bB  = (__hip_bfloat16*)(ws + 47185920);   // [4096,512]    s3-s5
    float*          kpe     = (float*)(ws + 51904512);            // [2048,64]     s2-s6
    __hip_bfloat16* q_lat   = (__hip_bfloat16*)(ws + 52428800);   // [2048,1536]   s2-s4
    __hip_bfloat16* vT2     = (__hip_bfloat16*)(ws + 52428800);   // [16][256][128]c s7-s8
    __hip_bfloat16* ckv     = (__hip_bfloat16*)(ws + 58720256);   // [2048,512]    s2-s5
    float* po0 = (float*)(ws + 25165824);   // 288 pids * 32KB
    float* po1 = (float*)(ws + 47185920);   // 160 pids * 32KB
    float* po2 = (float*)(ws + 12582912);   //  64 pids * 32KB
    float* pm  = (float*)(ws + 14680064);   // 512*64*4
    float* pl  = (float*)(ws + 14811136);   // 512*64*4

    dim3 blk(256);
    cvt_bf16<<<8192, blk, 0, stream>>>(hidden, hiddenB, 2097152);
    cvt_prep_a<<<8704, blk, 0, stream>>>(wq_a, wkv_a, W0);
    zero_f32<<<4224, blk, 0, stream>>>(fused, 1081344);
    gemm_lds<2><<<dim3(17, 16, 2), blk, 0, stream>>>(hiddenB, W0, fused, 4096, 2112, 2112, 32);
    post_fused<<<4608, blk, 0, stream>>>(fused, q_a_w, kv_a_w, q_lat, ckv, kpe);
    cvt_prep_b<<<6656, blk, 0, stream>>>(wq_b, wkv_b, wq_bB, wkv_bB);
    gemm_lds<0><<<dim3(24, 16), blk, 0, stream>>>(q_lat, wq_bB,  qb,     1536, 3072, 3072, 24);
    gemm_lds<0><<<dim3(32, 16), blk, 0, stream>>>(ckv,   wkv_bB, kv_exp,  512, 4096, 4096,  8);
    rope_assemble<<<2048, blk, 0, stream>>>(qb, kv_exp, kpe, kfT);
    transpose_v<<<dim3(32, 2, 16), blk, 0, stream>>>(kv_exp, vT2);
    attn_kernel<<<dim3(768), blk, 0, stream>>>(qb, kfT, vT2, attn_o, po0, po1, po2, pm, pl);
    attn_merge<<<dim3(256), blk, 0, stream>>>(po0, po1, po2, pm, pl, attn_o);
    cvt_bf16<<<8192, blk, 0, stream>>>(wo, woB, 2097152);
    gemm_lds<1><<<dim3(32, 16), blk, 0, stream>>>(attn_o, woB, out, 2048, 4096, 4096, 32);
}

// Round 8
// 408.937 us; speedup vs baseline: 1.0856x; 1.0856x over previous
//
#include <hip/hip_runtime.h>
#include <hip/hip_bf16.h>

// MLA prefill: B=1, S=2048, H=4096, NH=16, QK_NOPE=128, QK_ROPE=64, V=128
// f32 device tensors; bf16 MFMA internally. Attention: split-K flash (768
// blocks, every block <=16 K-steps) + f32 partial merge. GEMMs: m97 128x128
// tile, single-buffer gll staging (round-7 dbuf regressed: 64KB LDS made the
// 544-grid's 3rd-block-per-CU serialize -> wall 96 steps; reverted) +
// bijective XCD-chunked swizzle (T1/m204). Launch fusion: 11 dispatches.

typedef short bf16x8 __attribute__((ext_vector_type(8)));
typedef float f32x4  __attribute__((ext_vector_type(4)));

#if __has_builtin(__builtin_amdgcn_global_load_lds)
#define USE_GLL 1
#else
#define USE_GLL 0
#endif

__device__ __forceinline__ void stage16(const void* g, void* l) {
#if USE_GLL
    __builtin_amdgcn_global_load_lds(
        (__attribute__((address_space(1))) void*)(g),
        (__attribute__((address_space(3))) void*)(l), 16, 0, 0);
#else
    *(uint4*)l = *(const uint4*)g;
#endif
}

#define LOG2E 1.4426950408889634f

__device__ __forceinline__ short bf16_bits(float v) {
    union { __hip_bfloat16 h; short s; } u;
    u.h = __float2bfloat16(v);
    return u.s;
}

// Partial-O storage split across free workspace gaps (f32, 32KB/pid).
__device__ __forceinline__ const float* po_base(const float* b0, const float* b1,
                                                const float* b2, int pid) {
    if (pid < 288) return b0 + (size_t)pid * 8192;
    if (pid < 448) return b1 + (size_t)(pid - 288) * 8192;
    return b2 + (size_t)(pid - 448) * 8192;
}

// ---------------------------------------------------------------------------
// Elementwise helpers
// ---------------------------------------------------------------------------
__device__ __forceinline__ void cvt4(const float* __restrict__ s,
                                     __hip_bfloat16* __restrict__ d, int i) {
    float4 v = ((const float4*)s)[i];
    union { uint2 u; __hip_bfloat16 h[4]; } r;
    r.h[0] = __float2bfloat16(v.x); r.h[1] = __float2bfloat16(v.y);
    r.h[2] = __float2bfloat16(v.z); r.h[3] = __float2bfloat16(v.w);
    ((uint2*)d)[i] = r.u;
}

__global__ __launch_bounds__(256)
void cvt_bf16(const float* __restrict__ s, __hip_bfloat16* __restrict__ d, int nq) {
    int i = blockIdx.x * 256 + threadIdx.x;
    if (i < nq) cvt4(s, d, i);
}

// Fused stage-0 prep: [0,8192) hidden cvt, [8192,16896) wq_a+wkv_a cvt + pad,
// [16896,21120) zero fused. All outputs disjoint.
__global__ __launch_bounds__(256)
void prep_all(const float* __restrict__ hidden, __hip_bfloat16* __restrict__ hiddenB,
              const float* __restrict__ wq_a, const float* __restrict__ wkv_a,
              __hip_bfloat16* __restrict__ W0, float* __restrict__ fused) {
    const int b = blockIdx.x;
    if (b < 8192) {
        int i = b * 256 + threadIdx.x;            // 2097152 exact
        cvt4(hidden, hiddenB, i);
    } else if (b < 16896) {
        int i = (b - 8192) * 256 + threadIdx.x;   // 2228224 exact
        if (i < 1572864)       cvt4(wq_a, W0, i);
        else if (i < 2162688) {
            float4 v = ((const float4*)wkv_a)[i - 1572864];
            union { uint2 u; __hip_bfloat16 h[4]; } r;
            r.h[0] = __float2bfloat16(v.x); r.h[1] = __float2bfloat16(v.y);
            r.h[2] = __float2bfloat16(v.z); r.h[3] = __float2bfloat16(v.w);
            ((uint2*)W0)[i] = r.u;
        } else                 ((uint2*)W0)[i] = make_uint2(0u, 0u);
    } else {
        int i = (b - 16896) * 256 + threadIdx.x;  // 1081344 exact
        ((float4*)fused)[i] = float4{0.f, 0.f, 0.f, 0.f};
    }
}

// wq_b (1179648 quads) + wkv_b (524288 quads)
__global__ __launch_bounds__(256)
void cvt_prep_b(const float* __restrict__ wq_b, const float* __restrict__ wkv_b,
                __hip_bfloat16* __restrict__ wq_bB, __hip_bfloat16* __restrict__ wkv_bB) {
    int i = blockIdx.x * 256 + threadIdx.x;   // 1703936 total
    if (i >= 1703936) return;
    if (i < 1179648) cvt4(wq_b, wq_bB, i);
    else             cvt4(wkv_b, wkv_bB, i - 1179648);
}

// ---------------------------------------------------------------------------
// m97-style GEMM: C = A[M,K] * B[*,K]^T, bf16 in, fp32 acc, 128x128 tile,
// single-buffer gll staging. OUTMODE: 0=bf16, 1=f32, 2=f32 atomicAdd.
// Bijective XCD-chunked swizzle (m204).
// ---------------------------------------------------------------------------
template<int OUTMODE>
__global__ __launch_bounds__(256)
void gemm_lds(const __hip_bfloat16* __restrict__ A,
              const __hip_bfloat16* __restrict__ B,
              void* __restrict__ C,
              int K, int Cld, int Nlim, int ksteps) {
    __shared__ __align__(16) short As[128 * 64];
    __shared__ __align__(16) short Bs[128 * 64];

    const int tid  = threadIdx.x;
    const int lane = tid & 63;
    const int wave = tid >> 6;
    const int quad = lane >> 4;
    const int l16  = lane & 15;

    // XCD-chunked bijective remap of the flat block id
    const int gx = gridDim.x, gy = gridDim.y;
    const int nwg = gx * gy * gridDim.z;
    const int f   = blockIdx.x + gx * (blockIdx.y + gy * blockIdx.z);
    const int qc  = nwg >> 3, rc = nwg & 7;
    const int xcd = f & 7, idx = f >> 3;
    const int neu = (xcd < rc ? xcd * (qc + 1) : rc * (qc + 1) + (xcd - rc) * qc) + idx;
    const int bx  = neu % gx;
    const int t1  = neu / gx;
    const int by  = t1 % gy;
    const int bz  = t1 / gy;

    const int m0 = by * 128;
    const int n0 = bx * 128;
    const int wm = (wave >> 1) * 64;
    const int wn = (wave & 1) * 64;
    const int kbeg = bz * ksteps * 64;

    const int lrow = lane >> 3;
    const int lchk = lane & 7;
    const int sb   = (lchk ^ lrow) * 16;

    f32x4 acc[4][4];
    #pragma unroll
    for (int i = 0; i < 4; i++)
        #pragma unroll
        for (int j = 0; j < 4; j++)
            acc[i][j] = f32x4{0.f, 0.f, 0.f, 0.f};

    const size_t str = (size_t)K * 2;
    const char* Ab = (const char*)A;
    const char* Bb = (const char*)B;

    for (int kk = 0; kk < ksteps; kk++) {
        if (kk) __syncthreads();
        const size_t koff = (size_t)(kbeg + kk * 64) * 2;
        #pragma unroll
        for (int t = 0; t < 4; t++) {
            const int row = wave * 32 + t * 8 + lrow;
            stage16(Ab + (size_t)(m0 + row) * str + koff + sb,
                    (char*)As + row * 128 + lchk * 16);
            stage16(Bb + (size_t)(n0 + row) * str + koff + sb,
                    (char*)Bs + row * 128 + lchk * 16);
        }
        __syncthreads();

        #pragma unroll
        for (int ks = 0; ks < 2; ks++) {
            const int ca = ((ks * 4 + quad) ^ (l16 & 7)) * 8;
            bf16x8 af[4], bfr[4];
            #pragma unroll
            for (int mi = 0; mi < 4; mi++)
                af[mi] = *(const bf16x8*)(&As[(wm + mi * 16 + l16) * 64 + ca]);
            #pragma unroll
            for (int ni = 0; ni < 4; ni++)
                bfr[ni] = *(const bf16x8*)(&Bs[(wn + ni * 16 + l16) * 64 + ca]);
            #pragma unroll
            for (int mi = 0; mi < 4; mi++)
                #pragma unroll
                for (int ni = 0; ni < 4; ni++)
                    acc[mi][ni] = __builtin_amdgcn_mfma_f32_16x16x32_bf16(
                        af[mi], bfr[ni], acc[mi][ni], 0, 0, 0);
        }
    }

    #pragma unroll
    for (int mi = 0; mi < 4; mi++)
        #pragma unroll
        for (int ni = 0; ni < 4; ni++) {
            const int col = n0 + wn + ni * 16 + l16;
            if (col >= Nlim) continue;
            #pragma unroll
            for (int r = 0; r < 4; r++) {
                const int row = m0 + wm + mi * 16 + quad * 4 + r;
                const float v = acc[mi][ni][r];
                if (OUTMODE == 0)
                    ((__hip_bfloat16*)C)[(size_t)row * Cld + col] = __float2bfloat16(v);
                else if (OUTMODE == 1)
                    ((float*)C)[(size_t)row * Cld + col] = v;
                else
                    atomicAdd(&((float*)C)[(size_t)row * Cld + col], v);
            }
        }
}

// ---------------------------------------------------------------------------
// Fused post-GEMM: blocks [0,2048)=rms(q_lat), [2048,4096)=rms(ckv),
// [4096,4608)=kpe copy.
// ---------------------------------------------------------------------------
__global__ __launch_bounds__(256)
void post_fused(const float* __restrict__ fused,
                const float* __restrict__ qw, const float* __restrict__ kvw,
                __hip_bfloat16* __restrict__ q_lat, __hip_bfloat16* __restrict__ ckv,
                float* __restrict__ kpe) {
    const int b = blockIdx.x;
    if (b >= 4096) {
        int i = (b - 4096) * 256 + threadIdx.x;   // 131072 total
        int r = i >> 6, c = i & 63;
        kpe[i] = fused[(size_t)r * 2112 + 2048 + c];
        return;
    }
    const bool isq = (b < 2048);
    const int row = isq ? b : b - 2048;
    const int W  = isq ? 1536 : 512;
    const float* x = fused + (size_t)row * 2112 + (isq ? 0 : 1536);
    const float* w = isq ? qw : kvw;
    __hip_bfloat16* Y = (isq ? q_lat + (size_t)row * 1536 : ckv + (size_t)row * 512);
    float ss = 0.f;
    for (int i = threadIdx.x; i < W; i += 256) { float v = x[i]; ss += v * v; }
    for (int off = 32; off; off >>= 1) ss += __shfl_down(ss, off);
    __shared__ float red[4];
    int lane = threadIdx.x & 63, wv = threadIdx.x >> 6;
    if (lane == 0) red[wv] = ss;
    __syncthreads();
    float tot = red[0] + red[1] + red[2] + red[3];
    float inv = rsqrtf(tot / (float)W + 1e-6f);
    for (int i = threadIdx.x; i < W; i += 256)
        Y[i] = __float2bfloat16(x[i] * inv * w[i]);
}

// ---------------------------------------------------------------------------
// Fused: [0,2048) RoPE (q in-place) + kfT build (s = b);
//        [2048,3072) V transpose into vT2 (b2 = b - 2048).
// ---------------------------------------------------------------------------
__global__ __launch_bounds__(256)
void rope_trans(__hip_bfloat16* __restrict__ q,           // [S,16,192] in-place
                const __hip_bfloat16* __restrict__ kvexp, // [S,16,256]
                const float* __restrict__ kpe_in,         // [S,64]
                __hip_bfloat16* __restrict__ kfT,         // [16][24][2048] cells
                __hip_bfloat16* __restrict__ vT2) {       // [16][256][128] cells
    const int b = blockIdx.x;
    const int tid = threadIdx.x;
    if (b < 2048) {
        const int s = b;
        __shared__ float cs[32], sn[32];
        __shared__ __hip_bfloat16 kpe[64];
        if (tid < 32) {
            float inv = expf(-(float)tid * (logf(10000.0f) / 32.0f));
            float ang = (float)s * inv;
            cs[tid] = cosf(ang);
            sn[tid] = sinf(ang);
        }
        __syncthreads();
        if (tid < 32) {
            float x1 = kpe_in[(size_t)s * 64 + tid];
            float x2 = kpe_in[(size_t)s * 64 + 32 + tid];
            kpe[tid]      = __float2bfloat16(x1 * cs[tid] - x2 * sn[tid]);
            kpe[tid + 32] = __float2bfloat16(x2 * cs[tid] + x1 * sn[tid]);
        }
        for (int p = tid; p < 512; p += 256) {
            int h = p >> 5, j = p & 31;
            size_t base = (size_t)s * 3072 + h * 192 + 128;
            float x1 = __bfloat162float(q[base + j]);
            float x2 = __bfloat162float(q[base + j + 32]);
            q[base + j]      = __float2bfloat16(x1 * cs[j] - x2 * sn[j]);
            q[base + j + 32] = __float2bfloat16(x2 * cs[j] + x1 * sn[j]);
        }
        __syncthreads();
        for (int i = tid; i < 16 * 192; i += 256) {
            int h = i / 192, d = i % 192;
            __hip_bfloat16 v = (d < 128) ? kvexp[(size_t)s * 4096 + h * 256 + d]
                                         : kpe[d - 128];
            kfT[((size_t)(h * 24 + (d >> 3)) * 2048 + s) * 8 + (d & 7)] = v;
        }
    } else {
        const int b2 = b - 2048;                  // 1024 blocks: x=32,y=2,z=16
        const int s0 = (b2 & 31) * 64;
        const int d0 = ((b2 >> 5) & 1) * 64;
        const int h  = b2 >> 6;
        __shared__ short t[64 * 72];
        int c  = tid & 63;
        int r4 = tid >> 6;
        for (int i = 0; i < 16; i++) {
            int r = r4 * 16 + i;
            t[r * 72 + c] = *(const short*)&kvexp[(size_t)(s0 + r) * 4096 + h * 256 + 128 + d0 + c];
        }
        __syncthreads();
        for (int it = 0; it < 2; it++) {
            int scl = it * 4 + (tid >> 6);
            int d   = tid & 63;
            union { uint4 u; short sh[8]; } pk;
            #pragma unroll
            for (int e = 0; e < 8; e++) pk.sh[e] = t[(scl * 8 + e) * 72 + d];
            size_t cell = ((size_t)h * 256 + (b2 & 31) * 8 + scl) * 128 + d0 + d;
            ((uint4*)vT2)[cell] = pk.u;
        }
    }
}

// ---------------------------------------------------------------------------
// Flash attention, split-K: 768 blocks (see round-4 comment).
// ---------------------------------------------------------------------------
__global__ __launch_bounds__(256, 3)
void attn_kernel(const __hip_bfloat16* __restrict__ qb,   // [S,16,192]
                 const __hip_bfloat16* __restrict__ kfT,  // [16][24][2048] cells
                 const __hip_bfloat16* __restrict__ vT2,  // [16][256][128] cells
                 __hip_bfloat16* __restrict__ out,        // [S,16,128]
                 float* __restrict__ po0, float* __restrict__ po1,
                 float* __restrict__ po2,
                 float* __restrict__ pm, float* __restrict__ pl) {
    const int b = blockIdx.x;
    int h, qt, ktbeg, ktend, pid;
    if (b < 256) {
        h = b >> 4; qt = b & 15;
        ktbeg = 0; ktend = qt + 1; pid = -1;
    } else {
        const int idx  = (b - 256) & 255;
        const int part = (b - 256) >> 8;
        h = idx >> 4; qt = 31 - (idx & 15);
        const int n0 = (qt + 2) >> 1;          // ceil((qt+1)/2)
        ktbeg = part ? n0 : 0;
        ktend = part ? qt + 1 : n0;
        pid = part * 256 + idx;
    }
    const int q0   = qt * 64;
    const int tid  = threadIdx.x;
    const int wave = tid >> 6;
    const int lane = tid & 63;
    const int quad = lane >> 4;
    const int l16  = lane & 15;

    __shared__ __align__(16) short Ks2[24 * 64 * 8];   // 24 KB
    __shared__ __align__(16) short Vs2[ 8 * 128 * 8];  // 16 KB
    __shared__ __align__(16) short Ps2[ 8 * 64 * 8];   //  8 KB

    const float scale = 0.07216878364870322f;  // 192^-0.5

    // Q fragments, pre-scaled: A[m=l16][k=quad*8+j]
    bf16x8 qfr[6];
    {
        int row = q0 + wave * 16 + l16;
        const __hip_bfloat16* qrow = qb + ((size_t)row * 16 + h) * 192;
        for (int ks = 0; ks < 6; ks++) {
            union { bf16x8 v; __hip_bfloat16 h8[8]; } u;
            u.v = *(const bf16x8*)(qrow + ks * 32 + quad * 8);
            #pragma unroll
            for (int e = 0; e < 8; e++)
                u.h8[e] = __float2bfloat16(__bfloat162float(u.h8[e]) * scale);
            qfr[ks] = u.v;
        }
    }

    f32x4 o_acc[8];
    #pragma unroll
    for (int i = 0; i < 8; i++) o_acc[i] = f32x4{0.f, 0.f, 0.f, 0.f};
    float m_i[4], l_i[4];
    #pragma unroll
    for (int r = 0; r < 4; r++) { m_i[r] = -__builtin_inff(); l_i[r] = 0.f; }

    const char* kfb = (const char*)kfT;
    const char* vtb = (const char*)vT2;

    for (int kt = ktbeg; kt < ktend; kt++) {
        if (kt != ktbeg) __syncthreads();
        #pragma unroll
        for (int j = 0; j < 6; j++) {
            int c = wave * 6 + j;
            stage16(kfb + (((size_t)(h * 24 + c) * 2048) + kt * 64 + lane) * 16,
                    (char*)Ks2 + (c * 64 + lane) * 16);
        }
        #pragma unroll
        for (int j = 0; j < 4; j++) {
            int c  = wave * 2 + (j >> 1);
            int hd = j & 1;
            stage16(vtb + (((size_t)(h * 256 + kt * 8 + c) * 128) + hd * 64 + lane) * 16,
                    (char*)Vs2 + (c * 128 + hd * 64 + lane) * 16);
        }
        __syncthreads();

        f32x4 sc[4];
        #pragma unroll
        for (int n = 0; n < 4; n++) sc[n] = f32x4{0.f, 0.f, 0.f, 0.f};
        #pragma unroll
        for (int ks = 0; ks < 6; ks++)
            #pragma unroll
            for (int n = 0; n < 4; n++) {
                bf16x8 kb = *(const bf16x8*)(&Ks2[((ks * 4 + quad) * 64 + n * 16 + l16) * 8]);
                sc[n] = __builtin_amdgcn_mfma_f32_16x16x32_bf16(qfr[ks], kb, sc[n], 0, 0, 0);
            }

        const bool last = (kt == qt);
        float tmax[4], rsum[4], alpha[4];
        #pragma unroll
        for (int r = 0; r < 4; r++) tmax[r] = -__builtin_inff();
        #pragma unroll
        for (int n = 0; n < 4; n++)
            #pragma unroll
            for (int r = 0; r < 4; r++) {
                float v = sc[n][r];
                if (last && (kt * 64 + n * 16 + l16) > (q0 + wave * 16 + quad * 4 + r))
                    v = -__builtin_inff();
                sc[n][r] = v;
                tmax[r] = fmaxf(tmax[r], v);
            }
        #pragma unroll
        for (int r = 0; r < 4; r++)
            #pragma unroll
            for (int off = 1; off < 16; off <<= 1)
                tmax[r] = fmaxf(tmax[r], __shfl_xor(tmax[r], off));
        #pragma unroll
        for (int r = 0; r < 4; r++) {
            float mn = fmaxf(m_i[r], tmax[r]);
            alpha[r] = exp2f((m_i[r] - mn) * LOG2E);
            m_i[r] = mn;
            rsum[r] = 0.f;
        }
        #pragma unroll
        for (int n = 0; n < 4; n++)
            #pragma unroll
            for (int r = 0; r < 4; r++) {
                float p2 = exp2f((sc[n][r] - m_i[r]) * LOG2E);
                sc[n][r] = p2;
                rsum[r] += p2;
            }
        #pragma unroll
        for (int r = 0; r < 4; r++) {
            #pragma unroll
            for (int off = 1; off < 16; off <<= 1)
                rsum[r] += __shfl_xor(rsum[r], off);
            l_i[r] = l_i[r] * alpha[r] + rsum[r];
        }
        #pragma unroll
        for (int n = 0; n < 4; n++)
            #pragma unroll
            for (int r = 0; r < 4; r++)
                Ps2[((n * 2 + (l16 >> 3)) * 64 + wave * 16 + quad * 4 + r) * 8 + (l16 & 7)] =
                    bf16_bits(sc[n][r]);
        #pragma unroll
        for (int d = 0; d < 8; d++)
            #pragma unroll
            for (int r = 0; r < 4; r++)
                o_acc[d][r] *= alpha[r];
        #pragma unroll
        for (int ks2 = 0; ks2 < 2; ks2++) {
            bf16x8 pa = *(const bf16x8*)(&Ps2[((ks2 * 4 + quad) * 64 + wave * 16 + l16) * 8]);
            #pragma unroll
            for (int dg = 0; dg < 8; dg++) {
                bf16x8 vb = *(const bf16x8*)(&Vs2[((ks2 * 4 + quad) * 128 + dg * 16 + l16) * 8]);
                o_acc[dg] = __builtin_amdgcn_mfma_f32_16x16x32_bf16(pa, vb, o_acc[dg], 0, 0, 0);
            }
        }
    }

    if (pid < 0) {
        #pragma unroll
        for (int dg = 0; dg < 8; dg++)
            #pragma unroll
            for (int r = 0; r < 4; r++) {
                int row = q0 + wave * 16 + quad * 4 + r;
                float v = o_acc[dg][r] / l_i[r];
                out[((size_t)row * 16 + h) * 128 + dg * 16 + l16] = __float2bfloat16(v);
            }
    } else {
        float* pob = const_cast<float*>(po_base(po0, po1, po2, pid));
        #pragma unroll
        for (int dg = 0; dg < 8; dg++)
            #pragma unroll
            for (int r = 0; r < 4; r++) {
                int lr = wave * 16 + quad * 4 + r;
                pob[(size_t)lr * 128 + dg * 16 + l16] = o_acc[dg][r];
            }
        if (l16 == 0) {
            #pragma unroll
            for (int r = 0; r < 4; r++) {
                int lr = wave * 16 + quad * 4 + r;
                pm[pid * 64 + lr] = m_i[r];
                pl[pid * 64 + lr] = l_i[r];
            }
        }
    }
}

// ---------------------------------------------------------------------------
__global__ __launch_bounds__(256)
void attn_merge(const float* __restrict__ po0, const float* __restrict__ po1,
                const float* __restrict__ po2,
                const float* __restrict__ pm, const float* __restrict__ pl,
                __hip_bfloat16* __restrict__ out) {
    const int idx = blockIdx.x;            // 0..255
    const int h  = idx >> 4;
    const int qt = 31 - (idx & 15);
    const int q0 = qt * 64;
    const int t   = threadIdx.x;
    const int row = t >> 2;
    const int c0  = (t & 3) << 5;
    const int pid0 = idx, pid1 = 256 + idx;
    const float m0 = pm[pid0 * 64 + row], m1 = pm[pid1 * 64 + row];
    const float l0 = pl[pid0 * 64 + row], l1 = pl[pid1 * 64 + row];
    const float M  = fmaxf(m0, m1);
    const float e0 = exp2f((m0 - M) * LOG2E);
    const float e1 = exp2f((m1 - M) * LOG2E);
    const float inv = 1.f / (e0 * l0 + e1 * l1);
    const float* p0 = po_base(po0, po1, po2, pid0) + (size_t)row * 128 + c0;
    const float* p1 = po_base(po0, po1, po2, pid1) + (size_t)row * 128 + c0;
    __hip_bfloat16* o = out + ((size_t)(q0 + row) * 16 + h) * 128 + c0;
    #pragma unroll
    for (int c = 0; c < 32; c += 4) {
        float4 a = *(const float4*)(p0 + c);
        float4 bb = *(const float4*)(p1 + c);
        union { uint2 u; __hip_bfloat16 hh[4]; } w;
        w.hh[0] = __float2bfloat16((e0 * a.x + e1 * bb.x) * inv);
        w.hh[1] = __float2bfloat16((e0 * a.y + e1 * bb.y) * inv);
        w.hh[2] = __float2bfloat16((e0 * a.z + e1 * bb.z) * inv);
        w.hh[3] = __float2bfloat16((e0 * a.w + e1 * bb.w) * inv);
        *(uint2*)(o + c) = w.u;
    }
}

// ---------------------------------------------------------------------------
extern "C" void kernel_launch(void* const* d_in, const int* in_sizes, int n_in,
                              void* d_out, int out_size, void* d_ws, size_t ws_size,
                              hipStream_t stream) {
    const float* hidden = (const float*)d_in[0];
    const float* wq_a   = (const float*)d_in[2];
    const float* q_a_w  = (const float*)d_in[3];
    const float* wq_b   = (const float*)d_in[4];
    const float* wkv_a  = (const float*)d_in[5];
    const float* kv_a_w = (const float*)d_in[6];
    const float* wkv_b  = (const float*)d_in[7];
    const float* wo     = (const float*)d_in[8];
    float* out = (float*)d_out;

    char* ws = (char*)d_ws;
    __hip_bfloat16* hiddenB = (__hip_bfloat16*)(ws + 0);          // [2048,4096]   s0-s1
    __hip_bfloat16* wq_bB   = (__hip_bfloat16*)(ws + 0);          // [3072,1536]   s3-s4
    __hip_bfloat16* kfT     = (__hip_bfloat16*)(ws + 0);          // [16][24][2048]c s6-s8
    __hip_bfloat16* W0      = (__hip_bfloat16*)(ws + 16777216);   // [2176,4096]   s0-s1
    __hip_bfloat16* kv_exp  = (__hip_bfloat16*)(ws + 16777216);   // [2048,16,256] s5-s7
    __hip_bfloat16* attn_o  = (__hip_bfloat16*)(ws + 16777216);   // [2048,2048]   s8-s9
    float*          fused   = (float*)(ws + 34603008);            // [2048,2112]   s1-s2
    __hip_bfloat16* qb      = (__hip_bfloat16*)(ws + 34603008);   // [2048,16,192] s4-s8
    __hip_bfloat16* woB     = (__hip_bfloat16*)(ws + 34603008);   // [4096,2048]   s9
    __hip_bfloat16* wkv_bB  = (__hip_bfloat16*)(ws + 47185920);   // [4096,512]    s3-s5
    float*          kpe     = (float*)(ws + 51904512);            // [2048,64]     s2-s6
    __hip_bfloat16* q_lat   = (__hip_bfloat16*)(ws + 52428800);   // [2048,1536]   s2-s4
    __hip_bfloat16* vT2     = (__hip_bfloat16*)(ws + 52428800);   // [16][256][128]c s7-s8
    __hip_bfloat16* ckv     = (__hip_bfloat16*)(ws + 58720256);   // [2048,512]    s2-s5
    float* po0 = (float*)(ws + 25165824);   // 288 pids * 32KB
    float* po1 = (float*)(ws + 47185920);   // 160 pids * 32KB
    float* po2 = (float*)(ws + 12582912);   //  64 pids * 32KB
    float* pm  = (float*)(ws + 14680064);   // 512*64*4
    float* pl  = (float*)(ws + 14811136);   // 512*64*4

    dim3 blk(256);
    prep_all<<<21120, blk, 0, stream>>>(hidden, hiddenB, wq_a, wkv_a, W0, fused);
    gemm_lds<2><<<dim3(17, 16, 2), blk, 0, stream>>>(hiddenB, W0, fused, 4096, 2112, 2112, 32);
    post_fused<<<4608, blk, 0, stream>>>(fused, q_a_w, kv_a_w, q_lat, ckv, kpe);
    cvt_prep_b<<<6656, blk, 0, stream>>>(wq_b, wkv_b, wq_bB, wkv_bB);
    gemm_lds<0><<<dim3(24, 16), blk, 0, stream>>>(q_lat, wq_bB,  qb,     1536, 3072, 3072, 24);
    gemm_lds<0><<<dim3(32, 16), blk, 0, stream>>>(ckv,   wkv_bB, kv_exp,  512, 4096, 4096,  8);
    rope_trans<<<3072, blk, 0, stream>>>(qb, kv_exp, kpe, kfT, vT2);
    attn_kernel<<<dim3(768), blk, 0, stream>>>(qb, kfT, vT2, attn_o, po0, po1, po2, pm, pl);
    attn_merge<<<dim3(256), blk, 0, stream>>>(po0, po1, po2, pm, pl, attn_o);
    cvt_bf16<<<8192, blk, 0, stream>>>(wo, woB, 2097152);
    gemm_lds<1><<<dim3(32, 16), blk, 0, stream>>>(attn_o, woB, out, 2048, 4096, 4096, 32);
}